// Round 7
// baseline (77.994 us; speedup 1.0000x reference)
//
#include <hip/hip_runtime.h>

#define NPTS   65536
#define KNN    8
#define CDIM   64
#define SHB    9
#define NCODES 8192
#define NPHASE 4
#define PSHIFT 11  // 2048 codes/slice -> 2.6 MB slice fits 4 MB per-XCD L2
#define PTSW   8   // points per wave
#define WAVES  4
#define NBLK   (NPTS / (PTSW * WAVES))   // 2048 blocks -> 8 blocks/CU
#define LSTRIDE 80 // per-point LDS: ids u16[8]@0, wbar f32[8]@16, smh u32[4]@48, sm8 f32@64, mask u32@68

#if defined(__has_builtin)
#if __has_builtin(__builtin_amdgcn_fdot2)
#define HAS_FDOT2 1
#endif
#endif

typedef _Float16 half2v __attribute__((ext_vector_type(2)));

static __device__ __forceinline__ unsigned int pk16(float a, float b) {
    union { unsigned int u; _Float16 h[2]; } x;
    x.h[0] = (_Float16)a; x.h[1] = (_Float16)b;
    return x.u;
}
static __device__ __forceinline__ half2v as_h2(unsigned int u) {
    union { unsigned int u; half2v h; } x; x.u = u; return x.h;
}

// recA: (8192, 64) x 16 B  -> dwords (s0,s1)(s2,s3)(s4,s5)(s6,s7), lane-contiguous
// recB: (8192, 64) x  4 B  -> dword (s8, code)

__global__ __launch_bounds__(256) void repack_kernel(
    const float* __restrict__ codes,   // (8192,64)
    const float* __restrict__ shc,     // (8192,576)
    unsigned int* __restrict__ recA,   // (8192*256) dwords
    unsigned int* __restrict__ recB)   // (8192*64) dwords
{
    const int wid  = threadIdx.x >> 6;
    const int lane = threadIdx.x & 63;   // dim
    const int c    = blockIdx.x * 4 + wid;

    const float* p = shc + (size_t)c * (CDIM * SHB) + lane * SHB;
    float v[SHB];
#pragma unroll
    for (int s = 0; s < SHB; ++s) v[s] = p[s];
    const float cv = codes[c * CDIM + lane];

    uint4 a;
    a.x = pk16(v[0], v[1]);
    a.y = pk16(v[2], v[3]);
    a.z = pk16(v[4], v[5]);
    a.w = pk16(v[6], v[7]);
    *reinterpret_cast<uint4*>(recA + (size_t)c * 256 + 4 * lane) = a;
    recB[(size_t)c * 64 + lane] = pk16(v[8], cv);
}

// Phased gather kernel, batched-issue variant: per point, ALL predicated
// gather loads issue back-to-back (compile-time-unrolled k, wave-uniform
// predicates, statically-indexed register arrays), then one wait + consume.
// Removes the serial ctz->readfirstlane->load dependency chain of R6.
__global__ __launch_bounds__(256) void shcode_phased4(
    const float* __restrict__ qp,
    const float* __restrict__ vd,
    const float* __restrict__ cpos,
    const unsigned int* __restrict__ recA,
    const unsigned int* __restrict__ recB,
    const int*   __restrict__ knn,
    float* __restrict__ out)
{
    __shared__ unsigned char lds[WAVES * PTSW * LSTRIDE];   // 2560 B

    const int tid   = threadIdx.x;
    const int lane  = tid & 63;
    const int wid   = tid >> 6;
    const int pbase = (blockIdx.x * WAVES + wid) * PTSW;

    // ---- precompute: lane l (< PTSW) owns point pbase+l ----
    if (lane < PTSW) {
        const int n = pbase + lane;
        unsigned char* pr = lds + (wid * PTSW + lane) * LSTRIDE;
        unsigned short* ids16 = (unsigned short*)(pr + 0);
        float*          wbar  = (float*)(pr + 16);
        unsigned int*   smh   = (unsigned int*)(pr + 48);
        float*          sm8p  = (float*)(pr + 64);
        unsigned int*   maskp = (unsigned int*)(pr + 68);

        const float qx = qp[n * 3 + 0];
        const float qy = qp[n * 3 + 1];
        const float qz = qp[n * 3 + 2];

        int   ids[KNN];
        float w[KNN];
        float wsum = 0.0f;
#pragma unroll
        for (int k = 0; k < KNN; ++k) {
            const int id = knn[n * KNN + k];
            ids[k] = id;
            const float dx = qx - cpos[id * 3 + 0];
            const float dy = qy - cpos[id * 3 + 1];
            const float dz = qz - cpos[id * 3 + 2];
            w[k] = 1.0f / (dx * dx + dy * dy + dz * dz + 1e-16f);
            wsum += w[k];
        }
        const float inv = 1.0f / wsum;
        unsigned int mask = 0u;
#pragma unroll
        for (int k = 0; k < KNN; ++k) {
            ids16[k] = (unsigned short)ids[k];
            wbar[k]  = w[k] * inv;
            mask |= 1u << (((unsigned)ids[k] >> PSHIFT) * 8 + k);
        }
        *maskp = mask;

        const float x = vd[n * 3 + 0];
        const float y = vd[n * 3 + 1];
        const float z = vd[n * 3 + 2];
        const float xx = x * x, yy = y * y, zz = z * z;
        smh[0] = pk16(0.28209479177387814f,           -0.4886025119029199f * y);
        smh[1] = pk16(0.4886025119029199f * z,        -0.4886025119029199f * x);
        smh[2] = pk16(1.0925484305920792f * (x * y),  -1.0925484305920792f * (y * z));
        smh[3] = pk16(0.31539156525252005f * (2.0f * zz - xx - yy),
                      -1.0925484305920792f * (x * z));
        *sm8p  = 0.5462742152960396f * (xx - yy);
    }
    __syncthreads();

    float acc_c[PTSW], acc_s[PTSW];
#pragma unroll
    for (int p = 0; p < PTSW; ++p) { acc_c[p] = 0.0f; acc_s[p] = 0.0f; }

    for (int ph = 0; ph < NPHASE; ++ph) {
#pragma unroll
        for (int p = 0; p < PTSW; ++p) {
            const unsigned char* pr = lds + (wid * PTSW + p) * LSTRIDE;
            const unsigned int mask =
                (unsigned int)__builtin_amdgcn_readfirstlane(
                    (int)*(const unsigned int*)(pr + 68));
            const unsigned int m8 = (mask >> (8 * ph)) & 0xffu;
            if (!m8) continue;                      // uniform scalar branch

            // ---- issue pass: all predicated gathers back-to-back ----
            uint4        A[KNN];
            unsigned int B[KNN];
            float        wk[KNN];
#pragma unroll
            for (int k = 0; k < KNN; ++k) {
                if ((m8 >> k) & 1u) {
                    const int id = __builtin_amdgcn_readfirstlane(
                        (int)((const unsigned short*)pr)[k]);
                    A[k]  = *reinterpret_cast<const uint4*>(
                        recA + (size_t)id * 256 + 4 * lane);
                    B[k]  = recB[(size_t)id * 64 + lane];
                    wk[k] = ((const float*)(pr + 16))[k];
                }
            }

            // ---- consume pass ----
            const unsigned int* smu = (const unsigned int*)(pr + 48);
            const half2v smh0 = as_h2(smu[0]);
            const half2v smh1 = as_h2(smu[1]);
            const half2v smh2 = as_h2(smu[2]);
            const half2v smh3 = as_h2(smu[3]);
            const float  sm8f = *(const float*)(pr + 64);

#pragma unroll
            for (int k = 0; k < KNN; ++k) {
                if ((m8 >> k) & 1u) {
                    const half2v b2 = as_h2(B[k]);
                    const float f8 = (float)b2[0];
                    const float fc = (float)b2[1];
#ifdef HAS_FDOT2
                    float agg = sm8f * f8;
                    agg = __builtin_amdgcn_fdot2(as_h2(A[k].w), smh3, agg, false);
                    agg = __builtin_amdgcn_fdot2(as_h2(A[k].z), smh2, agg, false);
                    agg = __builtin_amdgcn_fdot2(as_h2(A[k].y), smh1, agg, false);
                    agg = __builtin_amdgcn_fdot2(as_h2(A[k].x), smh0, agg, false);
#else
                    const half2v a0 = as_h2(A[k].x), a1 = as_h2(A[k].y);
                    const half2v a2 = as_h2(A[k].z), a3 = as_h2(A[k].w);
                    float agg = sm8f * f8;
                    agg += (float)a0[0] * (float)smh0[0] + (float)a0[1] * (float)smh0[1];
                    agg += (float)a1[0] * (float)smh1[0] + (float)a1[1] * (float)smh1[1];
                    agg += (float)a2[0] * (float)smh2[0] + (float)a2[1] * (float)smh2[1];
                    agg += (float)a3[0] * (float)smh3[0] + (float)a3[1] * (float)smh3[1];
#endif
                    acc_s[p] += wk[k] * agg;
                    acc_c[p] += wk[k] * fc;
                }
            }
        }
        __syncthreads();   // keep block's waves phase-aligned
    }

#pragma unroll
    for (int p = 0; p < PTSW; ++p) {
        const int n = pbase + p;
        __builtin_nontemporal_store(acc_c[p], &out[n * CDIM + lane]);
        __builtin_nontemporal_store(acc_s[p],
                                    &out[(size_t)NPTS * CDIM + n * CDIM + lane]);
    }
}

// --- fallback (round-1 fp32 direct-gather) if workspace too small ---
__global__ __launch_bounds__(256) void shcode_kernel(
    const float* __restrict__ qp, const float* __restrict__ vd,
    const float* __restrict__ cpos, const float* __restrict__ codes,
    const float* __restrict__ shc, const int* __restrict__ knn,
    float* __restrict__ out)
{
    const int wid  = threadIdx.x >> 6;
    const int lane = threadIdx.x & 63;
    const int n    = blockIdx.x * 4 + wid;

    const float x = vd[n * 3 + 0], y = vd[n * 3 + 1], z = vd[n * 3 + 2];
    const float xx = x * x, yy = y * y, zz = z * z;
    const float sm0 = 0.28209479177387814f;
    const float sm1 = -0.4886025119029199f * y;
    const float sm2 =  0.4886025119029199f * z;
    const float sm3 = -0.4886025119029199f * x;
    const float sm4 =  1.0925484305920792f * (x * y);
    const float sm5 = -1.0925484305920792f * (y * z);
    const float sm6 =  0.31539156525252005f * (2.0f * zz - xx - yy);
    const float sm7 = -1.0925484305920792f * (x * z);
    const float sm8 =  0.5462742152960396f * (xx - yy);

    const float qx = qp[n * 3 + 0], qy = qp[n * 3 + 1], qz = qp[n * 3 + 2];

    int idx[KNN]; float w[KNN]; float wsum = 0.0f;
#pragma unroll
    for (int k = 0; k < KNN; ++k) {
        int id = __builtin_amdgcn_readfirstlane(knn[n * KNN + k]);
        idx[k] = id;
        const float dx = qx - cpos[id * 3 + 0];
        const float dy = qy - cpos[id * 3 + 1];
        const float dz = qz - cpos[id * 3 + 2];
        const float sd = dx * dx + dy * dy + dz * dz + 1e-16f;
        w[k] = 1.0f / sd; wsum += w[k];
    }
    const float winv = 1.0f / wsum;

    float acc_c = 0.0f, acc_s = 0.0f;
#pragma unroll
    for (int k = 0; k < KNN; ++k) {
        const float wk = w[k] * winv;
        acc_c += wk * codes[(size_t)idx[k] * CDIM + lane];
        const float* p = shc + (size_t)idx[k] * (CDIM * SHB) + lane * SHB;
        acc_s += wk * (sm0 * p[0] + sm1 * p[1] + sm2 * p[2]
                     + sm3 * p[3] + sm4 * p[4] + sm5 * p[5]
                     + sm6 * p[6] + sm7 * p[7] + sm8 * p[8]);
    }
    out[n * CDIM + lane] = acc_c;
    out[(size_t)NPTS * CDIM + n * CDIM + lane] = acc_s;
}

extern "C" void kernel_launch(void* const* d_in, const int* in_sizes, int n_in,
                              void* d_out, int out_size, void* d_ws, size_t ws_size,
                              hipStream_t stream) {
    const float* qp    = (const float*)d_in[0];
    const float* vd    = (const float*)d_in[1];
    const float* cpos  = (const float*)d_in[2];
    const float* codes = (const float*)d_in[3];
    const float* shc   = (const float*)d_in[4];
    const int*   knn   = (const int*)d_in[6];
    float* out = (float*)d_out;

    const size_t recA_bytes = (size_t)NCODES * 256 * 4;  // 8 MB
    const size_t recB_bytes = (size_t)NCODES * 64 * 4;   // 2 MB

    if (ws_size >= recA_bytes + recB_bytes) {
        unsigned int* recA = (unsigned int*)d_ws;
        unsigned int* recB = (unsigned int*)((char*)d_ws + recA_bytes);
        hipLaunchKernelGGL(repack_kernel, dim3(NCODES / 4), dim3(256), 0, stream,
                           codes, shc, recA, recB);
        hipLaunchKernelGGL(shcode_phased4, dim3(NBLK), dim3(256), 0, stream,
                           qp, vd, cpos, recA, recB, knn, out);
    } else {
        hipLaunchKernelGGL(shcode_kernel, dim3(NPTS / 4), dim3(256), 0, stream,
                           qp, vd, cpos, codes, shc, knn, out);
    }
}